// Round 1
// baseline (391.059 us; speedup 1.0000x reference)
//
#include <hip/hip_runtime.h>
#include <math.h>

#define N_NODES 50000
#define N_EDGES 800000
#define HEADS 4
#define HID 64
#define FDIM 256      // HEADS*HID == F_IN == 256 for both layers
#define LDA 40        // padded LDS k-stride (halves): 80B row stride
#define SCAN_CHUNK 1024
#define SCAN_NB ((N_NODES + SCAN_CHUNK - 1) / SCAN_CHUNK)   // 49

typedef __attribute__((ext_vector_type(8))) _Float16 half8;
typedef __attribute__((ext_vector_type(4))) _Float16 half4;
typedef __attribute__((ext_vector_type(4))) float f32x4;

// ---------------------------------------------------------------- CSR build

__global__ __launch_bounds__(256) void hist_kernel(const int* __restrict__ dst,
                                                   int* __restrict__ counts, int E) {
    int i = blockIdx.x * blockDim.x + threadIdx.x;
    if (i < E) atomicAdd(&counts[dst[i]], 1);
}

__global__ __launch_bounds__(256) void scan_local(const int* __restrict__ counts,
                                                  int* __restrict__ offs,
                                                  int* __restrict__ bsum, int n) {
    __shared__ int part[256];
    const int b = blockIdx.x, t = threadIdx.x;
    const int base = b * SCAN_CHUNK + t * 4;
    int v[4];
#pragma unroll
    for (int j = 0; j < 4; j++) {
        int idx = base + j;
        v[j] = (idx < n) ? counts[idx] : 0;
    }
    int s0 = v[0], s1 = s0 + v[1], s2 = s1 + v[2], s3 = s2 + v[3];
    part[t] = s3;
    __syncthreads();
    for (int off = 1; off < 256; off <<= 1) {
        int x = (t >= off) ? part[t - off] : 0;
        __syncthreads();
        part[t] += x;
        __syncthreads();
    }
    int prefix = (t > 0) ? part[t - 1] : 0;
    int e[4] = {prefix, prefix + s0, prefix + s1, prefix + s2};
#pragma unroll
    for (int j = 0; j < 4; j++) {
        int idx = base + j;
        if (idx < n) offs[idx] = e[j];
    }
    if (t == 255) bsum[b] = part[255];
}

__global__ __launch_bounds__(64) void scan_bsum(int* __restrict__ bsum,
                                                int* __restrict__ offs, int nb, int n) {
    int lane = threadIdx.x;
    int own = (lane < nb) ? bsum[lane] : 0;
    int v = own;
    for (int off = 1; off < 64; off <<= 1) {
        int x = __shfl_up(v, off);
        if (lane >= off) v += x;
    }
    if (lane < nb) bsum[lane] = v - own;   // exclusive prefix
    if (lane == nb - 1) offs[n] = v;       // grand total
}

__global__ __launch_bounds__(256) void scan_add(int* __restrict__ offs,
                                                const int* __restrict__ bsum, int n) {
    const int b = blockIdx.x;
    const int p = bsum[b];
    const int base = b * SCAN_CHUNK + threadIdx.x * 4;
#pragma unroll
    for (int j = 0; j < 4; j++) {
        int idx = base + j;
        if (idx < n) offs[idx] += p;
    }
}

__global__ __launch_bounds__(256) void scatter_kernel(const int* __restrict__ src,
                                                      const int* __restrict__ dst,
                                                      const int* __restrict__ offs,
                                                      int* __restrict__ cursor,
                                                      int* __restrict__ csr_src, int E) {
    int i = blockIdx.x * blockDim.x + threadIdx.x;
    if (i < E) {
        int d = dst[i];
        int p = offs[d] + atomicAdd(&cursor[d], 1);
        csr_src[p] = src[i];
    }
}

// -------------------------------------------- prep: W transpose-cast, x cast

__global__ __launch_bounds__(256) void wcast_kernel(const float* __restrict__ W0,
                                                    const float* __restrict__ W1,
                                                    _Float16* __restrict__ wt0,
                                                    _Float16* __restrict__ wt1) {
    const float* W = blockIdx.y ? W1 : W0;
    _Float16* wt = blockIdx.y ? wt1 : wt0;
    int n = blockIdx.x * 16 + (threadIdx.x >> 4);
    int k0 = (threadIdx.x & 15) * 16;
    for (int j = 0; j < 16; j++)
        wt[n * FDIM + k0 + j] = (_Float16)W[(k0 + j) * FDIM + n];
}

__global__ __launch_bounds__(256) void cast_x_kernel(const float* __restrict__ x,
                                                     _Float16* __restrict__ x16) {
    size_t i = ((size_t)blockIdx.x * 256 + threadIdx.x) * 4;
    float4 v = *(const float4*)&x[i];
    half4 h = {(_Float16)v.x, (_Float16)v.y, (_Float16)v.z, (_Float16)v.w};
    *(half4*)&x16[i] = h;
}

// -------------------------------------------- fp16 MFMA GEMM + fused el/er
// C = A16 @ W (W pre-cast/transposed: Bt[n][k]). feat16 written fp16;
// el/er computed in the epilogue from fp32 accumulators (wave's 64-col
// quadrant == one head; width-16 shuffle completes the reduction).
__global__ __launch_bounds__(256) void mfma_gemm(const _Float16* __restrict__ A16,
                                                 const _Float16* __restrict__ Bt,
                                                 const float* __restrict__ al,
                                                 const float* __restrict__ ar,
                                                 _Float16* __restrict__ feat16,
                                                 float* __restrict__ el,
                                                 float* __restrict__ er) {
    __shared__ _Float16 ash[128][LDA];
    __shared__ _Float16 bsh[128][LDA];

    const int t = threadIdx.x;
    const int m0 = blockIdx.x * 128;
    const int n0 = blockIdx.y * 128;
    const int wave = t >> 6, lane = t & 63;
    const int quad = lane >> 4, l16 = lane & 15;
    const int wr = (wave >> 1) * 64;
    const int wc = (wave & 1) * 64;

    const f32x4 zero = {0.f, 0.f, 0.f, 0.f};
    f32x4 acc[4][4];
#pragma unroll
    for (int i = 0; i < 4; i++)
#pragma unroll
        for (int j = 0; j < 4; j++) acc[i][j] = zero;

    for (int kk = 0; kk < FDIM; kk += 32) {
        // stage A and B tiles: 128 rows x 32 halves each; thread does 2 x 16B per array
#pragma unroll
        for (int ii = 0; ii < 2; ii++) {
            int idx = t + ii * 256;          // 0..511
            int row = idx >> 2;
            int kb = (idx & 3) * 8;
            int gr = m0 + row; if (gr >= N_NODES) gr = N_NODES - 1;
            *(half8*)&ash[row][kb] = *(const half8*)&A16[(size_t)gr * FDIM + kk + kb];
            *(half8*)&bsh[row][kb] = *(const half8*)&Bt[(size_t)(n0 + row) * FDIM + kk + kb];
        }
        __syncthreads();

        half8 af[4], bf[4];
#pragma unroll
        for (int i = 0; i < 4; i++) {
            af[i] = *(half8*)&ash[wr + i * 16 + l16][quad * 8];
            bf[i] = *(half8*)&bsh[wc + i * 16 + l16][quad * 8];
        }
#pragma unroll
        for (int mt = 0; mt < 4; mt++)
#pragma unroll
            for (int nt = 0; nt < 4; nt++)
                acc[mt][nt] = __builtin_amdgcn_mfma_f32_16x16x32_f16(af[mt], bf[nt], acc[mt][nt], 0, 0, 0);
        __syncthreads();
    }

    // ---- epilogue: feat16 store + fused el/er (this wave's head = h)
    const int h = (n0 + wc) >> 6;
    float alv[4], arv[4];
#pragma unroll
    for (int nt = 0; nt < 4; nt++) {
        alv[nt] = al[n0 + wc + nt * 16 + l16];
        arv[nt] = ar[n0 + wc + nt * 16 + l16];
    }
#pragma unroll
    for (int mt = 0; mt < 4; mt++) {
        int m = m0 + wr + mt * 16 + quad * 4;
        float pl[4] = {0.f, 0.f, 0.f, 0.f}, pr[4] = {0.f, 0.f, 0.f, 0.f};
#pragma unroll
        for (int nt = 0; nt < 4; nt++) {
            int n = n0 + wc + nt * 16 + l16;
#pragma unroll
            for (int r = 0; r < 4; r++) {
                float v = acc[mt][nt][r];
                if (m + r < N_NODES) feat16[(size_t)(m + r) * FDIM + n] = (_Float16)v;
                pl[r] += v * alv[nt];
                pr[r] += v * arv[nt];
            }
        }
#pragma unroll
        for (int r = 0; r < 4; r++) {
            float a = pl[r], b = pr[r];
            for (int off = 8; off; off >>= 1) {
                a += __shfl_down(a, off, 16);
                b += __shfl_down(b, off, 16);
            }
            if (l16 == 0 && m + r < N_NODES) {
                el[(m + r) * 4 + h] = a;
                er[(m + r) * 4 + h] = b;
            }
        }
    }
}

// ------------------------------------------- fused softmax + aggregate
// Wave per node, NO LDS / NO barriers. Lane owns features f=lane*4..+3
// (head = lane>>4); every lane walks ALL edges, so the per-head softmax
// denominator is complete in-register (identical across the head's 16 lanes).
// Single-pass (no max subtraction — logits are O(1), ratio is max-invariant).
// mode 0: write h1 as fp16 (layer-2 GEMM input, lives in d_out)
// mode 1: final fp32 head-major write
__global__ __launch_bounds__(256) void agg_fused(const _Float16* __restrict__ feat16,
                                                 const float* __restrict__ el,
                                                 const float* __restrict__ er,
                                                 const float* __restrict__ bias,
                                                 const int* __restrict__ offs,
                                                 const int* __restrict__ csr_src,
                                                 float* __restrict__ out,
                                                 _Float16* __restrict__ h1,
                                                 int mode) {
    const int wave = threadIdx.x >> 6;
    const int lane = threadIdx.x & 63;
    const int n = blockIdx.x * 4 + wave;
    const int head = lane >> 4;
    const int f = lane * 4;           // == head*64 + (lane&15)*4
    const int beg = offs[n];
    const int end = offs[n + 1];
    const float er_h = er[n * 4 + head];

    float4 acc0 = make_float4(0.f, 0.f, 0.f, 0.f);
    float4 acc1 = make_float4(0.f, 0.f, 0.f, 0.f);
    float ss0 = 0.f, ss1 = 0.f;

    int i = beg;
    for (; i + 3 < end; i += 4) {
        int s0 = csr_src[i], s1 = csr_src[i + 1];
        int s2 = csr_src[i + 2], s3 = csr_src[i + 3];
        float e0 = el[s0 * 4 + head] + er_h;
        float e1 = el[s1 * 4 + head] + er_h;
        float e2 = el[s2 * 4 + head] + er_h;
        float e3 = el[s3 * 4 + head] + er_h;
        half4 v0 = *(const half4*)&feat16[(size_t)s0 * FDIM + f];
        half4 v1 = *(const half4*)&feat16[(size_t)s1 * FDIM + f];
        half4 v2 = *(const half4*)&feat16[(size_t)s2 * FDIM + f];
        half4 v3 = *(const half4*)&feat16[(size_t)s3 * FDIM + f];
        e0 = (e0 > 0.f) ? e0 : 0.2f * e0;
        e1 = (e1 > 0.f) ? e1 : 0.2f * e1;
        e2 = (e2 > 0.f) ? e2 : 0.2f * e2;
        e3 = (e3 > 0.f) ? e3 : 0.2f * e3;
        float w0 = __expf(e0), w1 = __expf(e1), w2 = __expf(e2), w3 = __expf(e3);
        ss0 += w0 + w2;
        ss1 += w1 + w3;
        acc0.x += w0 * (float)v0[0] + w2 * (float)v2[0];
        acc0.y += w0 * (float)v0[1] + w2 * (float)v2[1];
        acc0.z += w0 * (float)v0[2] + w2 * (float)v2[2];
        acc0.w += w0 * (float)v0[3] + w2 * (float)v2[3];
        acc1.x += w1 * (float)v1[0] + w3 * (float)v3[0];
        acc1.y += w1 * (float)v1[1] + w3 * (float)v3[1];
        acc1.z += w1 * (float)v1[2] + w3 * (float)v3[2];
        acc1.w += w1 * (float)v1[3] + w3 * (float)v3[3];
    }
    for (; i < end; i++) {
        int s0 = csr_src[i];
        float e0 = el[s0 * 4 + head] + er_h;
        half4 v0 = *(const half4*)&feat16[(size_t)s0 * FDIM + f];
        e0 = (e0 > 0.f) ? e0 : 0.2f * e0;
        float w0 = __expf(e0);
        ss0 += w0;
        acc0.x += w0 * (float)v0[0];
        acc0.y += w0 * (float)v0[1];
        acc0.z += w0 * (float)v0[2];
        acc0.w += w0 * (float)v0[3];
    }

    float S = fmaxf(ss0 + ss1, 1e-9f);
    float inv = 1.f / S;
    float4 bv = *(const float4*)&bias[f];
    float r0 = (acc0.x + acc1.x) * inv + bv.x;
    float r1 = (acc0.y + acc1.y) * inv + bv.y;
    float r2 = (acc0.z + acc1.z) * inv + bv.z;
    float r3 = (acc0.w + acc1.w) * inv + bv.w;
    r0 = (r0 > 0.f) ? r0 : expm1f(r0);
    r1 = (r1 > 0.f) ? r1 : expm1f(r1);
    r2 = (r2 > 0.f) ? r2 : expm1f(r2);
    r3 = (r3 > 0.f) ? r3 : expm1f(r3);

    if (mode) {
        const int d = (lane & 15) * 4;
        float4 rv = make_float4(r0, r1, r2, r3);
        *(float4*)&out[(size_t)head * N_NODES * HID + (size_t)n * HID + d] = rv;
    } else {
        half4 hv = {(_Float16)r0, (_Float16)r1, (_Float16)r2, (_Float16)r3};
        *(half4*)&h1[(size_t)n * FDIM + f] = hv;
    }
}

// ---------------------------------------------------------------- launch

extern "C" void kernel_launch(void* const* d_in, const int* in_sizes, int n_in,
                              void* d_out, int out_size, void* d_ws, size_t ws_size,
                              hipStream_t stream) {
    const float* x   = (const float*)d_in[0];
    const int*   src = (const int*)d_in[1];
    const int*   dst = (const int*)d_in[2];
    const float* W0  = (const float*)d_in[3];
    const float* al0 = (const float*)d_in[4];
    const float* ar0 = (const float*)d_in[5];
    const float* b0  = (const float*)d_in[6];
    const float* W1  = (const float*)d_in[7];
    const float* al1 = (const float*)d_in[8];
    const float* ar1 = (const float*)d_in[9];
    const float* b1  = (const float*)d_in[10];
    float* out = (float*)d_out;

    // x16 (pre-cast input) and later h1 (layer-1 hidden, fp16) both live in
    // the first 25.6 MB of d_out. Timeline: cast_x writes x16 -> gemm-1 reads
    // x16 -> agg(mode0) overwrites with h1 -> gemm-2 reads h1 -> agg(mode1)
    // overwrites all of d_out with the final output. All sequential on stream.
    _Float16* x16h1 = (_Float16*)d_out;

    // workspace layout
    _Float16* feat16 = (_Float16*)d_ws;                          // N*256 fp16
    _Float16* wt0 = feat16 + (size_t)N_NODES * FDIM;             // 256*256
    _Float16* wt1 = wt0 + FDIM * FDIM;                           // 256*256
    float* el    = (float*)(wt1 + FDIM * FDIM);                  // N*4
    float* er    = el + N_NODES * HEADS;                         // N*4
    int* counts  = (int*)(er + N_NODES * HEADS);                 // N
    int* cursor  = counts + N_NODES;                             // N
    int* offs    = cursor + N_NODES;                             // N+1 (pad 50016)
    int* bsum    = offs + 50016;                                 // 64
    int* csr_src = bsum + 64;                                    // E

    // ---- prep + CSR build
    hipMemsetAsync(counts, 0, 2 * N_NODES * sizeof(int), stream);  // counts + cursor
    wcast_kernel<<<dim3(16, 2), 256, 0, stream>>>(W0, W1, wt0, wt1);
    cast_x_kernel<<<N_NODES * FDIM / 1024, 256, 0, stream>>>(x, x16h1);
    hist_kernel<<<(N_EDGES + 255) / 256, 256, 0, stream>>>(dst, counts, N_EDGES);
    scan_local<<<SCAN_NB, 256, 0, stream>>>(counts, offs, bsum, N_NODES);
    scan_bsum<<<1, 64, 0, stream>>>(bsum, offs, SCAN_NB, N_NODES);
    scan_add<<<SCAN_NB, 256, 0, stream>>>(offs, bsum, N_NODES);
    scatter_kernel<<<(N_EDGES + 255) / 256, 256, 0, stream>>>(src, dst, offs, cursor, csr_src, N_EDGES);

    dim3 ggrid((N_NODES + 127) / 128, FDIM / 128);

    // ---- layer 1 (h1 fp16 written into d_out)
    mfma_gemm<<<ggrid, 256, 0, stream>>>(x16h1, wt0, al0, ar0, feat16, el, er);
    agg_fused<<<N_NODES / 4, 256, 0, stream>>>(feat16, el, er, b0, offs, csr_src,
                                               out, x16h1, 0);

    // ---- layer 2 (reads h1 fp16; final head-major fp32 write to d_out)
    mfma_gemm<<<ggrid, 256, 0, stream>>>(x16h1, wt1, al1, ar1, feat16, el, er);
    agg_fused<<<N_NODES / 4, 256, 0, stream>>>(feat16, el, er, b1, offs, csr_src,
                                               out, x16h1, 1);
}

// Round 2
// 390.184 us; speedup vs baseline: 1.0022x; 1.0022x over previous
//
#include <hip/hip_runtime.h>
#include <math.h>

#define N_NODES 50000
#define N_EDGES 800000
#define HEADS 4
#define HID 64
#define FDIM 256      // HEADS*HID == F_IN == 256 for both layers
#define LDA 40        // padded LDS k-stride (halves): 80B row stride
#define SCAN_CHUNK 1024
#define SCAN_NB ((N_NODES + SCAN_CHUNK - 1) / SCAN_CHUNK)   // 49

typedef __attribute__((ext_vector_type(8))) _Float16 half8;
typedef __attribute__((ext_vector_type(4))) _Float16 half4;
typedef __attribute__((ext_vector_type(4))) float f32x4;

// ---------------------------------------------------------------- CSR build

__global__ __launch_bounds__(256) void hist_kernel(const int* __restrict__ dst,
                                                   int* __restrict__ counts, int E) {
    int i = blockIdx.x * blockDim.x + threadIdx.x;
    if (i < E) atomicAdd(&counts[dst[i]], 1);
}

__global__ __launch_bounds__(256) void scan_local(const int* __restrict__ counts,
                                                  int* __restrict__ offs,
                                                  int* __restrict__ bsum, int n) {
    __shared__ int part[256];
    const int b = blockIdx.x, t = threadIdx.x;
    const int base = b * SCAN_CHUNK + t * 4;
    int v[4];
#pragma unroll
    for (int j = 0; j < 4; j++) {
        int idx = base + j;
        v[j] = (idx < n) ? counts[idx] : 0;
    }
    int s0 = v[0], s1 = s0 + v[1], s2 = s1 + v[2], s3 = s2 + v[3];
    part[t] = s3;
    __syncthreads();
    for (int off = 1; off < 256; off <<= 1) {
        int x = (t >= off) ? part[t - off] : 0;
        __syncthreads();
        part[t] += x;
        __syncthreads();
    }
    int prefix = (t > 0) ? part[t - 1] : 0;
    int e[4] = {prefix, prefix + s0, prefix + s1, prefix + s2};
#pragma unroll
    for (int j = 0; j < 4; j++) {
        int idx = base + j;
        if (idx < n) offs[idx] = e[j];
    }
    if (t == 255) bsum[b] = part[255];
}

__global__ __launch_bounds__(64) void scan_bsum(int* __restrict__ bsum,
                                                int* __restrict__ offs, int nb, int n) {
    int lane = threadIdx.x;
    int own = (lane < nb) ? bsum[lane] : 0;
    int v = own;
    for (int off = 1; off < 64; off <<= 1) {
        int x = __shfl_up(v, off);
        if (lane >= off) v += x;
    }
    if (lane < nb) bsum[lane] = v - own;   // exclusive prefix
    if (lane == nb - 1) offs[n] = v;       // grand total
}

__global__ __launch_bounds__(256) void scan_add(int* __restrict__ offs,
                                                const int* __restrict__ bsum, int n) {
    const int b = blockIdx.x;
    const int p = bsum[b];
    const int base = b * SCAN_CHUNK + threadIdx.x * 4;
#pragma unroll
    for (int j = 0; j < 4; j++) {
        int idx = base + j;
        if (idx < n) offs[idx] += p;
    }
}

__global__ __launch_bounds__(256) void scatter_kernel(const int* __restrict__ src,
                                                      const int* __restrict__ dst,
                                                      const int* __restrict__ offs,
                                                      int* __restrict__ cursor,
                                                      int* __restrict__ csr_src, int E) {
    int i = blockIdx.x * blockDim.x + threadIdx.x;
    if (i < E) {
        int d = dst[i];
        int p = offs[d] + atomicAdd(&cursor[d], 1);
        csr_src[p] = src[i];
    }
}

// -------------------------------------------- prep: W transpose-cast, x cast

__global__ __launch_bounds__(256) void wcast_kernel(const float* __restrict__ W0,
                                                    const float* __restrict__ W1,
                                                    _Float16* __restrict__ wt0,
                                                    _Float16* __restrict__ wt1) {
    const float* W = blockIdx.y ? W1 : W0;
    _Float16* wt = blockIdx.y ? wt1 : wt0;
    int n = blockIdx.x * 16 + (threadIdx.x >> 4);
    int k0 = (threadIdx.x & 15) * 16;
    for (int j = 0; j < 16; j++)
        wt[n * FDIM + k0 + j] = (_Float16)W[(k0 + j) * FDIM + n];
}

__global__ __launch_bounds__(256) void cast_x_kernel(const float* __restrict__ x,
                                                     _Float16* __restrict__ x16) {
    size_t i = ((size_t)blockIdx.x * 256 + threadIdx.x) * 4;
    float4 v = *(const float4*)&x[i];
    half4 h = {(_Float16)v.x, (_Float16)v.y, (_Float16)v.z, (_Float16)v.w};
    *(half4*)&x16[i] = h;
}

// -------------------------------------------- fp16 MFMA GEMM + fused el/er
// C = A16 @ W (W pre-cast/transposed: Bt[n][k]). feat16 written fp16;
// el/er computed in the epilogue from fp32 accumulators (wave's 64-col
// quadrant == one head; width-16 shuffle completes the reduction).
__global__ __launch_bounds__(256) void mfma_gemm(const _Float16* __restrict__ A16,
                                                 const _Float16* __restrict__ Bt,
                                                 const float* __restrict__ al,
                                                 const float* __restrict__ ar,
                                                 _Float16* __restrict__ feat16,
                                                 float* __restrict__ el,
                                                 float* __restrict__ er) {
    __shared__ _Float16 ash[128][LDA];
    __shared__ _Float16 bsh[128][LDA];

    const int t = threadIdx.x;
    const int m0 = blockIdx.x * 128;
    const int n0 = blockIdx.y * 128;
    const int wave = t >> 6, lane = t & 63;
    const int quad = lane >> 4, l16 = lane & 15;
    const int wr = (wave >> 1) * 64;
    const int wc = (wave & 1) * 64;

    const f32x4 zero = {0.f, 0.f, 0.f, 0.f};
    f32x4 acc[4][4];
#pragma unroll
    for (int i = 0; i < 4; i++)
#pragma unroll
        for (int j = 0; j < 4; j++) acc[i][j] = zero;

    for (int kk = 0; kk < FDIM; kk += 32) {
        // stage A and B tiles: 128 rows x 32 halves each; thread does 2 x 16B per array
#pragma unroll
        for (int ii = 0; ii < 2; ii++) {
            int idx = t + ii * 256;          // 0..511
            int row = idx >> 2;
            int kb = (idx & 3) * 8;
            int gr = m0 + row; if (gr >= N_NODES) gr = N_NODES - 1;
            *(half8*)&ash[row][kb] = *(const half8*)&A16[(size_t)gr * FDIM + kk + kb];
            *(half8*)&bsh[row][kb] = *(const half8*)&Bt[(size_t)(n0 + row) * FDIM + kk + kb];
        }
        __syncthreads();

        half8 af[4], bf[4];
#pragma unroll
        for (int i = 0; i < 4; i++) {
            af[i] = *(half8*)&ash[wr + i * 16 + l16][quad * 8];
            bf[i] = *(half8*)&bsh[wc + i * 16 + l16][quad * 8];
        }
#pragma unroll
        for (int mt = 0; mt < 4; mt++)
#pragma unroll
            for (int nt = 0; nt < 4; nt++)
                acc[mt][nt] = __builtin_amdgcn_mfma_f32_16x16x32_f16(af[mt], bf[nt], acc[mt][nt], 0, 0, 0);
        __syncthreads();
    }

    // ---- epilogue: feat16 store + fused el/er (this wave's head = h)
    const int h = (n0 + wc) >> 6;
    float alv[4], arv[4];
#pragma unroll
    for (int nt = 0; nt < 4; nt++) {
        alv[nt] = al[n0 + wc + nt * 16 + l16];
        arv[nt] = ar[n0 + wc + nt * 16 + l16];
    }
#pragma unroll
    for (int mt = 0; mt < 4; mt++) {
        int m = m0 + wr + mt * 16 + quad * 4;
        float pl[4] = {0.f, 0.f, 0.f, 0.f}, pr[4] = {0.f, 0.f, 0.f, 0.f};
#pragma unroll
        for (int nt = 0; nt < 4; nt++) {
            int n = n0 + wc + nt * 16 + l16;
#pragma unroll
            for (int r = 0; r < 4; r++) {
                float v = acc[mt][nt][r];
                if (m + r < N_NODES) feat16[(size_t)(m + r) * FDIM + n] = (_Float16)v;
                pl[r] += v * alv[nt];
                pr[r] += v * arv[nt];
            }
        }
#pragma unroll
        for (int r = 0; r < 4; r++) {
            float a = pl[r], b = pr[r];
            for (int off = 8; off; off >>= 1) {
                a += __shfl_down(a, off, 16);
                b += __shfl_down(b, off, 16);
            }
            if (l16 == 0 && m + r < N_NODES) {
                el[(m + r) * 4 + h] = a;
                er[(m + r) * 4 + h] = b;
            }
        }
    }
}

// ------------------------------------------- fused softmax + aggregate
// Wave per node, NO LDS / NO barriers. Lane owns features f=lane*4..+3
// (head = lane>>4).
//
// v2: cooperative weight computation. Edges are walked in chunks of 16.
// W-phase: lane (lane&15)==j computes the softmax weight of edge chunk+j
// for its OWN head (1 csr_src load + 1 el gather + 1 expf per 16 edges,
// instead of every lane redundantly doing it per edge). MAC-phase: s and w
// are broadcast from lane (head<<4)|j via __shfl. Softmax denominator is
// accumulated per-lane in the W-phase and reduced once across the 16-lane
// head group at the end (weights for different edges live in different
// lanes, so the sum over lanes == sum over edges).
// Single-pass (no max subtraction — logits are O(1), ratio is max-invariant).
// mode 0: write h1 as fp16 (layer-2 GEMM input, lives in d_out)
// mode 1: final fp32 head-major write
__global__ __launch_bounds__(256) void agg_fused(const _Float16* __restrict__ feat16,
                                                 const float* __restrict__ el,
                                                 const float* __restrict__ er,
                                                 const float* __restrict__ bias,
                                                 const int* __restrict__ offs,
                                                 const int* __restrict__ csr_src,
                                                 float* __restrict__ out,
                                                 _Float16* __restrict__ h1,
                                                 int mode) {
    const int wave = threadIdx.x >> 6;
    const int lane = threadIdx.x & 63;
    const int n = blockIdx.x * 4 + wave;
    const int head = lane >> 4;
    const int f = lane * 4;           // == head*64 + (lane&15)*4
    const int base16 = lane & 48;     // first lane of this head's 16-group
    const int j16 = lane & 15;
    const int beg = offs[n];
    const int end = offs[n + 1];
    const float er_h = er[n * 4 + head];

    float4 acc = make_float4(0.f, 0.f, 0.f, 0.f);
    float ss = 0.f;

    for (int c = beg; c < end; c += 16) {
        // ---- W-phase: this lane owns edge c + j16 (for its own head)
        int e = c + j16;
        int s_own = 0;
        float w_own = 0.f;
        if (e < end) {
            s_own = csr_src[e];
            float lg = el[s_own * 4 + head] + er_h;
            lg = (lg > 0.f) ? lg : 0.2f * lg;
            w_own = __expf(lg);
        }
        ss += w_own;

        int rem = end - c;
        if (rem > 16) rem = 16;

        // ---- MAC-phase: walk the chunk's edges, s/w via shuffle broadcast
        int j = 0;
        for (; j + 3 < rem; j += 4) {
            int s0 = __shfl(s_own, base16 + j);
            int s1 = __shfl(s_own, base16 + j + 1);
            int s2 = __shfl(s_own, base16 + j + 2);
            int s3 = __shfl(s_own, base16 + j + 3);
            float w0 = __shfl(w_own, base16 + j);
            float w1 = __shfl(w_own, base16 + j + 1);
            float w2 = __shfl(w_own, base16 + j + 2);
            float w3 = __shfl(w_own, base16 + j + 3);
            half4 v0 = *(const half4*)&feat16[(size_t)s0 * FDIM + f];
            half4 v1 = *(const half4*)&feat16[(size_t)s1 * FDIM + f];
            half4 v2 = *(const half4*)&feat16[(size_t)s2 * FDIM + f];
            half4 v3 = *(const half4*)&feat16[(size_t)s3 * FDIM + f];
            acc.x += w0 * (float)v0[0] + w1 * (float)v1[0];
            acc.y += w0 * (float)v0[1] + w1 * (float)v1[1];
            acc.z += w0 * (float)v0[2] + w1 * (float)v1[2];
            acc.w += w0 * (float)v0[3] + w1 * (float)v1[3];
            acc.x += w2 * (float)v2[0] + w3 * (float)v3[0];
            acc.y += w2 * (float)v2[1] + w3 * (float)v3[1];
            acc.z += w2 * (float)v2[2] + w3 * (float)v3[2];
            acc.w += w2 * (float)v2[3] + w3 * (float)v3[3];
        }
        for (; j < rem; j++) {
            int s0 = __shfl(s_own, base16 + j);
            float w0 = __shfl(w_own, base16 + j);
            half4 v0 = *(const half4*)&feat16[(size_t)s0 * FDIM + f];
            acc.x += w0 * (float)v0[0];
            acc.y += w0 * (float)v0[1];
            acc.z += w0 * (float)v0[2];
            acc.w += w0 * (float)v0[3];
        }
    }

    // ---- reduce softmax denominator across the 16-lane head group
    ss += __shfl_xor(ss, 1, 16);
    ss += __shfl_xor(ss, 2, 16);
    ss += __shfl_xor(ss, 4, 16);
    ss += __shfl_xor(ss, 8, 16);

    float S = fmaxf(ss, 1e-9f);
    float inv = 1.f / S;
    float4 bv = *(const float4*)&bias[f];
    float r0 = acc.x * inv + bv.x;
    float r1 = acc.y * inv + bv.y;
    float r2 = acc.z * inv + bv.z;
    float r3 = acc.w * inv + bv.w;
    r0 = (r0 > 0.f) ? r0 : expm1f(r0);
    r1 = (r1 > 0.f) ? r1 : expm1f(r1);
    r2 = (r2 > 0.f) ? r2 : expm1f(r2);
    r3 = (r3 > 0.f) ? r3 : expm1f(r3);

    if (mode) {
        const int d = (lane & 15) * 4;
        float4 rv = make_float4(r0, r1, r2, r3);
        *(float4*)&out[(size_t)head * N_NODES * HID + (size_t)n * HID + d] = rv;
    } else {
        half4 hv = {(_Float16)r0, (_Float16)r1, (_Float16)r2, (_Float16)r3};
        *(half4*)&h1[(size_t)n * FDIM + f] = hv;
    }
}

// ---------------------------------------------------------------- launch

extern "C" void kernel_launch(void* const* d_in, const int* in_sizes, int n_in,
                              void* d_out, int out_size, void* d_ws, size_t ws_size,
                              hipStream_t stream) {
    const float* x   = (const float*)d_in[0];
    const int*   src = (const int*)d_in[1];
    const int*   dst = (const int*)d_in[2];
    const float* W0  = (const float*)d_in[3];
    const float* al0 = (const float*)d_in[4];
    const float* ar0 = (const float*)d_in[5];
    const float* b0  = (const float*)d_in[6];
    const float* W1  = (const float*)d_in[7];
    const float* al1 = (const float*)d_in[8];
    const float* ar1 = (const float*)d_in[9];
    const float* b1  = (const float*)d_in[10];
    float* out = (float*)d_out;

    // x16 (pre-cast input) and later h1 (layer-1 hidden, fp16) both live in
    // the first 25.6 MB of d_out. Timeline: cast_x writes x16 -> gemm-1 reads
    // x16 -> agg(mode0) overwrites with h1 -> gemm-2 reads h1 -> agg(mode1)
    // overwrites all of d_out with the final output. All sequential on stream.
    _Float16* x16h1 = (_Float16*)d_out;

    // workspace layout
    _Float16* feat16 = (_Float16*)d_ws;                          // N*256 fp16
    _Float16* wt0 = feat16 + (size_t)N_NODES * FDIM;             // 256*256
    _Float16* wt1 = wt0 + FDIM * FDIM;                           // 256*256
    float* el    = (float*)(wt1 + FDIM * FDIM);                  // N*4
    float* er    = el + N_NODES * HEADS;                         // N*4
    int* counts  = (int*)(er + N_NODES * HEADS);                 // N
    int* cursor  = counts + N_NODES;                             // N
    int* offs    = cursor + N_NODES;                             // N+1 (pad 50016)
    int* bsum    = offs + 50016;                                 // 64
    int* csr_src = bsum + 64;                                    // E

    // ---- prep + CSR build
    hipMemsetAsync(counts, 0, 2 * N_NODES * sizeof(int), stream);  // counts + cursor
    wcast_kernel<<<dim3(16, 2), 256, 0, stream>>>(W0, W1, wt0, wt1);
    cast_x_kernel<<<N_NODES * FDIM / 1024, 256, 0, stream>>>(x, x16h1);
    hist_kernel<<<(N_EDGES + 255) / 256, 256, 0, stream>>>(dst, counts, N_EDGES);
    scan_local<<<SCAN_NB, 256, 0, stream>>>(counts, offs, bsum, N_NODES);
    scan_bsum<<<1, 64, 0, stream>>>(bsum, offs, SCAN_NB, N_NODES);
    scan_add<<<SCAN_NB, 256, 0, stream>>>(offs, bsum, N_NODES);
    scatter_kernel<<<(N_EDGES + 255) / 256, 256, 0, stream>>>(src, dst, offs, cursor, csr_src, N_EDGES);

    dim3 ggrid((N_NODES + 127) / 128, FDIM / 128);

    // ---- layer 1 (h1 fp16 written into d_out)
    mfma_gemm<<<ggrid, 256, 0, stream>>>(x16h1, wt0, al0, ar0, feat16, el, er);
    agg_fused<<<N_NODES / 4, 256, 0, stream>>>(feat16, el, er, b0, offs, csr_src,
                                               out, x16h1, 0);

    // ---- layer 2 (reads h1 fp16; final head-major fp32 write to d_out)
    mfma_gemm<<<ggrid, 256, 0, stream>>>(x16h1, wt1, al1, ar1, feat16, el, er);
    agg_fused<<<N_NODES / 4, 256, 0, stream>>>(feat16, el, er, b1, offs, csr_src,
                                               out, x16h1, 1);
}

// Round 3
// 387.673 us; speedup vs baseline: 1.0087x; 1.0065x over previous
//
#include <hip/hip_runtime.h>
#include <math.h>

#define N_NODES 50000
#define N_EDGES 800000
#define HEADS 4
#define HID 64
#define FDIM 256      // HEADS*HID == F_IN == 256 for both layers
#define LDA 40        // padded LDS k-stride (halves): 80B row stride
#define SCAN_CHUNK 1024
#define SCAN_NB ((N_NODES + SCAN_CHUNK - 1) / SCAN_CHUNK)   // 49

typedef __attribute__((ext_vector_type(8))) _Float16 half8;
typedef __attribute__((ext_vector_type(4))) _Float16 half4;
typedef __attribute__((ext_vector_type(4))) float f32x4;

// ---------------------------------------------------------------- CSR build

__global__ __launch_bounds__(256) void hist_kernel(const int* __restrict__ dst,
                                                   int* __restrict__ counts, int E) {
    int i = blockIdx.x * blockDim.x + threadIdx.x;
    if (i < E) atomicAdd(&counts[dst[i]], 1);
}

__global__ __launch_bounds__(256) void scan_local(const int* __restrict__ counts,
                                                  int* __restrict__ offs,
                                                  int* __restrict__ bsum, int n) {
    __shared__ int part[256];
    const int b = blockIdx.x, t = threadIdx.x;
    const int base = b * SCAN_CHUNK + t * 4;
    int v[4];
#pragma unroll
    for (int j = 0; j < 4; j++) {
        int idx = base + j;
        v[j] = (idx < n) ? counts[idx] : 0;
    }
    int s0 = v[0], s1 = s0 + v[1], s2 = s1 + v[2], s3 = s2 + v[3];
    part[t] = s3;
    __syncthreads();
    for (int off = 1; off < 256; off <<= 1) {
        int x = (t >= off) ? part[t - off] : 0;
        __syncthreads();
        part[t] += x;
        __syncthreads();
    }
    int prefix = (t > 0) ? part[t - 1] : 0;
    int e[4] = {prefix, prefix + s0, prefix + s1, prefix + s2};
#pragma unroll
    for (int j = 0; j < 4; j++) {
        int idx = base + j;
        if (idx < n) offs[idx] = e[j];
    }
    if (t == 255) bsum[b] = part[255];
}

__global__ __launch_bounds__(64) void scan_bsum(int* __restrict__ bsum,
                                                int* __restrict__ offs, int nb, int n) {
    int lane = threadIdx.x;
    int own = (lane < nb) ? bsum[lane] : 0;
    int v = own;
    for (int off = 1; off < 64; off <<= 1) {
        int x = __shfl_up(v, off);
        if (lane >= off) v += x;
    }
    if (lane < nb) bsum[lane] = v - own;   // exclusive prefix
    if (lane == nb - 1) offs[n] = v;       // grand total
}

__global__ __launch_bounds__(256) void scan_add(int* __restrict__ offs,
                                                const int* __restrict__ bsum, int n) {
    const int b = blockIdx.x;
    const int p = bsum[b];
    const int base = b * SCAN_CHUNK + threadIdx.x * 4;
#pragma unroll
    for (int j = 0; j < 4; j++) {
        int idx = base + j;
        if (idx < n) offs[idx] += p;
    }
}

__global__ __launch_bounds__(256) void scatter_kernel(const int* __restrict__ src,
                                                      const int* __restrict__ dst,
                                                      const int* __restrict__ offs,
                                                      int* __restrict__ cursor,
                                                      int* __restrict__ csr_src, int E) {
    int i = blockIdx.x * blockDim.x + threadIdx.x;
    if (i < E) {
        int d = dst[i];
        int p = offs[d] + atomicAdd(&cursor[d], 1);
        csr_src[p] = src[i];
    }
}

// -------------------------------------------- prep: W transpose-cast, x cast

__global__ __launch_bounds__(256) void wcast_kernel(const float* __restrict__ W0,
                                                    const float* __restrict__ W1,
                                                    _Float16* __restrict__ wt0,
                                                    _Float16* __restrict__ wt1) {
    const float* W = blockIdx.y ? W1 : W0;
    _Float16* wt = blockIdx.y ? wt1 : wt0;
    int n = blockIdx.x * 16 + (threadIdx.x >> 4);
    int k0 = (threadIdx.x & 15) * 16;
    for (int j = 0; j < 16; j++)
        wt[n * FDIM + k0 + j] = (_Float16)W[(k0 + j) * FDIM + n];
}

__global__ __launch_bounds__(256) void cast_x_kernel(const float* __restrict__ x,
                                                     _Float16* __restrict__ x16) {
    size_t i = ((size_t)blockIdx.x * 256 + threadIdx.x) * 4;
    float4 v = *(const float4*)&x[i];
    half4 h = {(_Float16)v.x, (_Float16)v.y, (_Float16)v.z, (_Float16)v.w};
    *(half4*)&x16[i] = h;
}

// -------------------------------------------- fp16 MFMA GEMM + fused el/er
// C = A16 @ W (W pre-cast/transposed: Bt[n][k]). feat16 written fp16;
// el/er computed in the epilogue from fp32 accumulators (wave's 64-col
// quadrant == one head; width-16 shuffle completes the reduction).
__global__ __launch_bounds__(256) void mfma_gemm(const _Float16* __restrict__ A16,
                                                 const _Float16* __restrict__ Bt,
                                                 const float* __restrict__ al,
                                                 const float* __restrict__ ar,
                                                 _Float16* __restrict__ feat16,
                                                 float* __restrict__ el,
                                                 float* __restrict__ er) {
    __shared__ _Float16 ash[128][LDA];
    __shared__ _Float16 bsh[128][LDA];

    const int t = threadIdx.x;
    const int m0 = blockIdx.x * 128;
    const int n0 = blockIdx.y * 128;
    const int wave = t >> 6, lane = t & 63;
    const int quad = lane >> 4, l16 = lane & 15;
    const int wr = (wave >> 1) * 64;
    const int wc = (wave & 1) * 64;

    const f32x4 zero = {0.f, 0.f, 0.f, 0.f};
    f32x4 acc[4][4];
#pragma unroll
    for (int i = 0; i < 4; i++)
#pragma unroll
        for (int j = 0; j < 4; j++) acc[i][j] = zero;

    for (int kk = 0; kk < FDIM; kk += 32) {
        // stage A and B tiles: 128 rows x 32 halves each; thread does 2 x 16B per array
#pragma unroll
        for (int ii = 0; ii < 2; ii++) {
            int idx = t + ii * 256;          // 0..511
            int row = idx >> 2;
            int kb = (idx & 3) * 8;
            int gr = m0 + row; if (gr >= N_NODES) gr = N_NODES - 1;
            *(half8*)&ash[row][kb] = *(const half8*)&A16[(size_t)gr * FDIM + kk + kb];
            *(half8*)&bsh[row][kb] = *(const half8*)&Bt[(size_t)(n0 + row) * FDIM + kk + kb];
        }
        __syncthreads();

        half8 af[4], bf[4];
#pragma unroll
        for (int i = 0; i < 4; i++) {
            af[i] = *(half8*)&ash[wr + i * 16 + l16][quad * 8];
            bf[i] = *(half8*)&bsh[wc + i * 16 + l16][quad * 8];
        }
#pragma unroll
        for (int mt = 0; mt < 4; mt++)
#pragma unroll
            for (int nt = 0; nt < 4; nt++)
                acc[mt][nt] = __builtin_amdgcn_mfma_f32_16x16x32_f16(af[mt], bf[nt], acc[mt][nt], 0, 0, 0);
        __syncthreads();
    }

    // ---- epilogue: feat16 store + fused el/er (this wave's head = h)
    const int h = (n0 + wc) >> 6;
    float alv[4], arv[4];
#pragma unroll
    for (int nt = 0; nt < 4; nt++) {
        alv[nt] = al[n0 + wc + nt * 16 + l16];
        arv[nt] = ar[n0 + wc + nt * 16 + l16];
    }
#pragma unroll
    for (int mt = 0; mt < 4; mt++) {
        int m = m0 + wr + mt * 16 + quad * 4;
        float pl[4] = {0.f, 0.f, 0.f, 0.f}, pr[4] = {0.f, 0.f, 0.f, 0.f};
#pragma unroll
        for (int nt = 0; nt < 4; nt++) {
            int n = n0 + wc + nt * 16 + l16;
#pragma unroll
            for (int r = 0; r < 4; r++) {
                float v = acc[mt][nt][r];
                if (m + r < N_NODES) feat16[(size_t)(m + r) * FDIM + n] = (_Float16)v;
                pl[r] += v * alv[nt];
                pr[r] += v * arv[nt];
            }
        }
#pragma unroll
        for (int r = 0; r < 4; r++) {
            float a = pl[r], b = pr[r];
            for (int off = 8; off; off >>= 1) {
                a += __shfl_down(a, off, 16);
                b += __shfl_down(b, off, 16);
            }
            if (l16 == 0 && m + r < N_NODES) {
                el[(m + r) * 4 + h] = a;
                er[(m + r) * 4 + h] = b;
            }
        }
    }
}

// ------------------------------------------- fused softmax + aggregate
// Wave per node, NO LDS / NO barriers. Lane owns features f=lane*4..+3
// (head = lane>>4).
//
// v3: cooperative weights (v2) + chunk-wide MLP. Per 16-edge chunk:
// W-phase as v2 (lane j computes edge c+j's weight for its own head).
// MAC-phase now broadcasts all 16 (s,w) pairs and ISSUES ALL 16 feat16
// gathers before consuming any — 16 outstanding loads/wave (was 4),
// hiding the ~600cy L3-hit gather latency. Branch-free: OOB lanes carry
// w_own=0, s_own=0, so tail-chunk extra loads hit row 0 (cache-resident)
// and contribute 0.
// Single-pass softmax (no max subtraction — logits are O(1)).
// mode 0: write h1 as fp16 (layer-2 GEMM input, lives in d_out)
// mode 1: final fp32 head-major write
__global__ __launch_bounds__(256) void agg_fused(const _Float16* __restrict__ feat16,
                                                 const float* __restrict__ el,
                                                 const float* __restrict__ er,
                                                 const float* __restrict__ bias,
                                                 const int* __restrict__ offs,
                                                 const int* __restrict__ csr_src,
                                                 float* __restrict__ out,
                                                 _Float16* __restrict__ h1,
                                                 int mode) {
    const int wave = threadIdx.x >> 6;
    const int lane = threadIdx.x & 63;
    const int n = blockIdx.x * 4 + wave;
    const int head = lane >> 4;
    const int f = lane * 4;           // == head*64 + (lane&15)*4
    const int base16 = lane & 48;     // first lane of this head's 16-group
    const int j16 = lane & 15;
    const int beg = offs[n];
    const int end = offs[n + 1];
    const float er_h = er[n * 4 + head];

    float4 acc = make_float4(0.f, 0.f, 0.f, 0.f);
    float ss = 0.f;

    for (int c = beg; c < end; c += 16) {
        // ---- W-phase: this lane owns edge c + j16 (for its own head)
        int e = c + j16;
        int s_own = 0;
        float w_own = 0.f;
        if (e < end) {
            s_own = csr_src[e];
            float lg = el[s_own * 4 + head] + er_h;
            lg = (lg > 0.f) ? lg : 0.2f * lg;
            w_own = __expf(lg);
        }
        ss += w_own;

        // ---- broadcast all 16 (s,w) and issue all 16 gathers up-front
        float wv[16];
        half4 v[16];
#pragma unroll
        for (int j = 0; j < 16; j++) {
            int sj = __shfl(s_own, base16 + j);
            wv[j] = __shfl(w_own, base16 + j);
            v[j] = *(const half4*)&feat16[(size_t)sj * FDIM + f];
        }
        // ---- consume
#pragma unroll
        for (int j = 0; j < 16; j++) {
            acc.x += wv[j] * (float)v[j][0];
            acc.y += wv[j] * (float)v[j][1];
            acc.z += wv[j] * (float)v[j][2];
            acc.w += wv[j] * (float)v[j][3];
        }
    }

    // ---- reduce softmax denominator across the 16-lane head group
    ss += __shfl_xor(ss, 1, 16);
    ss += __shfl_xor(ss, 2, 16);
    ss += __shfl_xor(ss, 4, 16);
    ss += __shfl_xor(ss, 8, 16);

    float S = fmaxf(ss, 1e-9f);
    float inv = 1.f / S;
    float4 bv = *(const float4*)&bias[f];
    float r0 = acc.x * inv + bv.x;
    float r1 = acc.y * inv + bv.y;
    float r2 = acc.z * inv + bv.z;
    float r3 = acc.w * inv + bv.w;
    r0 = (r0 > 0.f) ? r0 : expm1f(r0);
    r1 = (r1 > 0.f) ? r1 : expm1f(r1);
    r2 = (r2 > 0.f) ? r2 : expm1f(r2);
    r3 = (r3 > 0.f) ? r3 : expm1f(r3);

    if (mode) {
        const int d = (lane & 15) * 4;
        float4 rv = make_float4(r0, r1, r2, r3);
        *(float4*)&out[(size_t)head * N_NODES * HID + (size_t)n * HID + d] = rv;
    } else {
        half4 hv = {(_Float16)r0, (_Float16)r1, (_Float16)r2, (_Float16)r3};
        *(half4*)&h1[(size_t)n * FDIM + f] = hv;
    }
}

// ---------------------------------------------------------------- launch

extern "C" void kernel_launch(void* const* d_in, const int* in_sizes, int n_in,
                              void* d_out, int out_size, void* d_ws, size_t ws_size,
                              hipStream_t stream) {
    const float* x   = (const float*)d_in[0];
    const int*   src = (const int*)d_in[1];
    const int*   dst = (const int*)d_in[2];
    const float* W0  = (const float*)d_in[3];
    const float* al0 = (const float*)d_in[4];
    const float* ar0 = (const float*)d_in[5];
    const float* b0  = (const float*)d_in[6];
    const float* W1  = (const float*)d_in[7];
    const float* al1 = (const float*)d_in[8];
    const float* ar1 = (const float*)d_in[9];
    const float* b1  = (const float*)d_in[10];
    float* out = (float*)d_out;

    // x16 (pre-cast input) and later h1 (layer-1 hidden, fp16) both live in
    // the first 25.6 MB of d_out. Timeline: cast_x writes x16 -> gemm-1 reads
    // x16 -> agg(mode0) overwrites with h1 -> gemm-2 reads h1 -> agg(mode1)
    // overwrites all of d_out with the final output. All sequential on stream.
    _Float16* x16h1 = (_Float16*)d_out;

    // workspace layout
    _Float16* feat16 = (_Float16*)d_ws;                          // N*256 fp16
    _Float16* wt0 = feat16 + (size_t)N_NODES * FDIM;             // 256*256
    _Float16* wt1 = wt0 + FDIM * FDIM;                           // 256*256
    float* el    = (float*)(wt1 + FDIM * FDIM);                  // N*4
    float* er    = el + N_NODES * HEADS;                         // N*4
    int* counts  = (int*)(er + N_NODES * HEADS);                 // N
    int* cursor  = counts + N_NODES;                             // N
    int* offs    = cursor + N_NODES;                             // N+1 (pad 50016)
    int* bsum    = offs + 50016;                                 // 64
    int* csr_src = bsum + 64;                                    // E

    // ---- prep + CSR build
    hipMemsetAsync(counts, 0, 2 * N_NODES * sizeof(int), stream);  // counts + cursor
    wcast_kernel<<<dim3(16, 2), 256, 0, stream>>>(W0, W1, wt0, wt1);
    cast_x_kernel<<<N_NODES * FDIM / 1024, 256, 0, stream>>>(x, x16h1);
    hist_kernel<<<(N_EDGES + 255) / 256, 256, 0, stream>>>(dst, counts, N_EDGES);
    scan_local<<<SCAN_NB, 256, 0, stream>>>(counts, offs, bsum, N_NODES);
    scan_bsum<<<1, 64, 0, stream>>>(bsum, offs, SCAN_NB, N_NODES);
    scan_add<<<SCAN_NB, 256, 0, stream>>>(offs, bsum, N_NODES);
    scatter_kernel<<<(N_EDGES + 255) / 256, 256, 0, stream>>>(src, dst, offs, cursor, csr_src, N_EDGES);

    dim3 ggrid((N_NODES + 127) / 128, FDIM / 128);

    // ---- layer 1 (h1 fp16 written into d_out)
    mfma_gemm<<<ggrid, 256, 0, stream>>>(x16h1, wt0, al0, ar0, feat16, el, er);
    agg_fused<<<N_NODES / 4, 256, 0, stream>>>(feat16, el, er, b0, offs, csr_src,
                                               out, x16h1, 0);

    // ---- layer 2 (reads h1 fp16; final head-major fp32 write to d_out)
    mfma_gemm<<<ggrid, 256, 0, stream>>>(x16h1, wt1, al1, ar1, feat16, el, er);
    agg_fused<<<N_NODES / 4, 256, 0, stream>>>(feat16, el, er, b1, offs, csr_src,
                                               out, x16h1, 1);
}

// Round 5
// 378.918 us; speedup vs baseline: 1.0320x; 1.0231x over previous
//
#include <hip/hip_runtime.h>
#include <math.h>

#define N_NODES 50000
#define N_EDGES 800000
#define HEADS 4
#define HID 64
#define FDIM 256      // HEADS*HID == F_IN == 256 for both layers
#define LDA 40        // padded LDS k-stride (halves): 80B row stride
#define SCAN_CHUNK 1024
#define SCAN_NB ((N_NODES + SCAN_CHUNK - 1) / SCAN_CHUNK)   // 49

typedef __attribute__((ext_vector_type(8))) _Float16 half8;
typedef __attribute__((ext_vector_type(4))) _Float16 half4;
typedef __attribute__((ext_vector_type(4))) float f32x4;

// ---------------------------------------------------------------- CSR build

__global__ __launch_bounds__(256) void hist_kernel(const int* __restrict__ dst,
                                                   int* __restrict__ counts, int E) {
    int i = blockIdx.x * blockDim.x + threadIdx.x;
    if (i < E) atomicAdd(&counts[dst[i]], 1);
}

__global__ __launch_bounds__(256) void scan_local(const int* __restrict__ counts,
                                                  int* __restrict__ offs,
                                                  int* __restrict__ bsum, int n) {
    __shared__ int part[256];
    const int b = blockIdx.x, t = threadIdx.x;
    const int base = b * SCAN_CHUNK + t * 4;
    int v[4];
#pragma unroll
    for (int j = 0; j < 4; j++) {
        int idx = base + j;
        v[j] = (idx < n) ? counts[idx] : 0;
    }
    int s0 = v[0], s1 = s0 + v[1], s2 = s1 + v[2], s3 = s2 + v[3];
    part[t] = s3;
    __syncthreads();
    for (int off = 1; off < 256; off <<= 1) {
        int x = (t >= off) ? part[t - off] : 0;
        __syncthreads();
        part[t] += x;
        __syncthreads();
    }
    int prefix = (t > 0) ? part[t - 1] : 0;
    int e[4] = {prefix, prefix + s0, prefix + s1, prefix + s2};
#pragma unroll
    for (int j = 0; j < 4; j++) {
        int idx = base + j;
        if (idx < n) offs[idx] = e[j];
    }
    if (t == 255) bsum[b] = part[255];
}

__global__ __launch_bounds__(64) void scan_bsum(int* __restrict__ bsum,
                                                int* __restrict__ offs, int nb, int n) {
    int lane = threadIdx.x;
    int own = (lane < nb) ? bsum[lane] : 0;
    int v = own;
    for (int off = 1; off < 64; off <<= 1) {
        int x = __shfl_up(v, off);
        if (lane >= off) v += x;
    }
    if (lane < nb) bsum[lane] = v - own;   // exclusive prefix
    if (lane == nb - 1) offs[n] = v;       // grand total
}

__global__ __launch_bounds__(256) void scan_add(int* __restrict__ offs,
                                                const int* __restrict__ bsum, int n) {
    const int b = blockIdx.x;
    const int p = bsum[b];
    const int base = b * SCAN_CHUNK + threadIdx.x * 4;
#pragma unroll
    for (int j = 0; j < 4; j++) {
        int idx = base + j;
        if (idx < n) offs[idx] += p;
    }
}

__global__ __launch_bounds__(256) void scatter_kernel(const int* __restrict__ src,
                                                      const int* __restrict__ dst,
                                                      const int* __restrict__ offs,
                                                      int* __restrict__ cursor,
                                                      int* __restrict__ csr_src, int E) {
    int i = blockIdx.x * blockDim.x + threadIdx.x;
    if (i < E) {
        int d = dst[i];
        int p = offs[d] + atomicAdd(&cursor[d], 1);
        csr_src[p] = src[i];
    }
}

// -------------------------------------------- prep: W transpose-cast

__global__ __launch_bounds__(256) void wcast_kernel(const float* __restrict__ W0,
                                                    const float* __restrict__ W1,
                                                    _Float16* __restrict__ wt0,
                                                    _Float16* __restrict__ wt1) {
    const float* W = blockIdx.y ? W1 : W0;
    _Float16* wt = blockIdx.y ? wt1 : wt0;
    int n = blockIdx.x * 16 + (threadIdx.x >> 4);
    int k0 = (threadIdx.x & 15) * 16;
    for (int j = 0; j < 16; j++)
        wt[n * FDIM + k0 + j] = (_Float16)W[(k0 + j) * FDIM + n];
}

// -------------------------------------------- fp16 MFMA GEMM + fused el/er
// v4: BN=256 (whole N in one block), 512 threads / 8 waves, each wave a
// 64x64 sub-tile (wr = (wave>>2)*64, wc = (wave&3)*64). A tile staged ONCE
// per block (was twice with the 2-column grid). Template A32: stage A
// directly from fp32 (layer 1 — eliminates the separate cast_x pass).
// el/er fused in the epilogue as before (wave's 64-col quadrant == head).
template <int A32>
__global__ __launch_bounds__(512) void mfma_gemm(const _Float16* __restrict__ A16,
                                                 const float* __restrict__ Af,
                                                 const _Float16* __restrict__ Bt,
                                                 const float* __restrict__ al,
                                                 const float* __restrict__ ar,
                                                 _Float16* __restrict__ feat16,
                                                 float* __restrict__ el,
                                                 float* __restrict__ er) {
    __shared__ _Float16 ash[128][LDA];
    __shared__ _Float16 bsh[256][LDA];

    const int t = threadIdx.x;
    const int m0 = blockIdx.x * 128;
    const int wave = t >> 6, lane = t & 63;
    const int quad = lane >> 4, l16 = lane & 15;
    const int wr = (wave >> 2) * 64;
    const int wc = (wave & 3) * 64;

    const f32x4 zero = {0.f, 0.f, 0.f, 0.f};
    f32x4 acc[4][4];
#pragma unroll
    for (int i = 0; i < 4; i++)
#pragma unroll
        for (int j = 0; j < 4; j++) acc[i][j] = zero;

    for (int kk = 0; kk < FDIM; kk += 32) {
        // ---- stage A: 128 rows x 32 halves = 512 x 8-half chunks, 1/thread
        {
            int row = t >> 2;
            int kb = (t & 3) * 8;
            int gr = m0 + row; if (gr >= N_NODES) gr = N_NODES - 1;
            if (A32) {
                const float* p = &Af[(size_t)gr * FDIM + kk + kb];
                float4 f0 = *(const float4*)p;
                float4 f1 = *(const float4*)(p + 4);
                half8 hv = {(_Float16)f0.x, (_Float16)f0.y, (_Float16)f0.z, (_Float16)f0.w,
                            (_Float16)f1.x, (_Float16)f1.y, (_Float16)f1.z, (_Float16)f1.w};
                *(half8*)&ash[row][kb] = hv;
            } else {
                *(half8*)&ash[row][kb] = *(const half8*)&A16[(size_t)gr * FDIM + kk + kb];
            }
        }
        // ---- stage B: 256 rows x 32 halves = 1024 chunks, 2/thread
#pragma unroll
        for (int ii = 0; ii < 2; ii++) {
            int idx = t + ii * 512;
            int row = idx >> 2;
            int kb = (idx & 3) * 8;
            *(half8*)&bsh[row][kb] = *(const half8*)&Bt[(size_t)row * FDIM + kk + kb];
        }
        __syncthreads();

        half8 af[4], bf[4];
#pragma unroll
        for (int i = 0; i < 4; i++) {
            af[i] = *(half8*)&ash[wr + i * 16 + l16][quad * 8];
            bf[i] = *(half8*)&bsh[wc + i * 16 + l16][quad * 8];
        }
#pragma unroll
        for (int mt = 0; mt < 4; mt++)
#pragma unroll
            for (int nt = 0; nt < 4; nt++)
                acc[mt][nt] = __builtin_amdgcn_mfma_f32_16x16x32_f16(af[mt], bf[nt], acc[mt][nt], 0, 0, 0);
        __syncthreads();
    }

    // ---- epilogue: feat16 store + fused el/er (this wave's head = h)
    const int h = wc >> 6;
    float alv[4], arv[4];
#pragma unroll
    for (int nt = 0; nt < 4; nt++) {
        alv[nt] = al[wc + nt * 16 + l16];
        arv[nt] = ar[wc + nt * 16 + l16];
    }
#pragma unroll
    for (int mt = 0; mt < 4; mt++) {
        int m = m0 + wr + mt * 16 + quad * 4;
        float pl[4] = {0.f, 0.f, 0.f, 0.f}, pr[4] = {0.f, 0.f, 0.f, 0.f};
#pragma unroll
        for (int nt = 0; nt < 4; nt++) {
            int n = wc + nt * 16 + l16;
#pragma unroll
            for (int r = 0; r < 4; r++) {
                float v = acc[mt][nt][r];
                if (m + r < N_NODES) feat16[(size_t)(m + r) * FDIM + n] = (_Float16)v;
                pl[r] += v * alv[nt];
                pr[r] += v * arv[nt];
            }
        }
#pragma unroll
        for (int r = 0; r < 4; r++) {
            float a = pl[r], b = pr[r];
            for (int off = 8; off; off >>= 1) {
                a += __shfl_down(a, off, 16);
                b += __shfl_down(b, off, 16);
            }
            if (l16 == 0 && m + r < N_NODES) {
                el[(m + r) * 4 + h] = a;
                er[(m + r) * 4 + h] = b;
            }
        }
    }
}

// ------------------------------------------- fused softmax + aggregate
// Wave per node, NO LDS / NO barriers. Lane owns features f=lane*4..+3
// (head = lane>>4).
//
// v2 (best measured; v3's 16-deep MLP regressed — stage is beyond-L2
// traffic-bound, invariant to scheduling): cooperative weights. Edges
// walked in 16-chunks; W-phase: lane (lane&15)==j computes edge c+j's
// weight for its OWN head; MAC-phase broadcasts (s,w) via __shfl, 4-wide.
// Denominator accumulated per-lane, reduced once at the end.
// Single-pass softmax (no max subtraction — logits are O(1)).
// mode 0: write h1 as fp16 (layer-2 GEMM input, lives in d_out)
// mode 1: final fp32 head-major write
__global__ __launch_bounds__(256) void agg_fused(const _Float16* __restrict__ feat16,
                                                 const float* __restrict__ el,
                                                 const float* __restrict__ er,
                                                 const float* __restrict__ bias,
                                                 const int* __restrict__ offs,
                                                 const int* __restrict__ csr_src,
                                                 float* __restrict__ out,
                                                 _Float16* __restrict__ h1,
                                                 int mode) {
    const int wave = threadIdx.x >> 6;
    const int lane = threadIdx.x & 63;
    const int n = blockIdx.x * 4 + wave;
    const int head = lane >> 4;
    const int f = lane * 4;           // == head*64 + (lane&15)*4
    const int base16 = lane & 48;     // first lane of this head's 16-group
    const int j16 = lane & 15;
    const int beg = offs[n];
    const int end = offs[n + 1];
    const float er_h = er[n * 4 + head];

    float4 acc = make_float4(0.f, 0.f, 0.f, 0.f);
    float ss = 0.f;

    for (int c = beg; c < end; c += 16) {
        // ---- W-phase: this lane owns edge c + j16 (for its own head)
        int e = c + j16;
        int s_own = 0;
        float w_own = 0.f;
        if (e < end) {
            s_own = csr_src[e];
            float lg = el[s_own * 4 + head] + er_h;
            lg = (lg > 0.f) ? lg : 0.2f * lg;
            w_own = __expf(lg);
        }
        ss += w_own;

        int rem = end - c;
        if (rem > 16) rem = 16;

        // ---- MAC-phase: walk the chunk's edges, s/w via shuffle broadcast
        int j = 0;
        for (; j + 3 < rem; j += 4) {
            int s0 = __shfl(s_own, base16 + j);
            int s1 = __shfl(s_own, base16 + j + 1);
            int s2 = __shfl(s_own, base16 + j + 2);
            int s3 = __shfl(s_own, base16 + j + 3);
            float w0 = __shfl(w_own, base16 + j);
            float w1 = __shfl(w_own, base16 + j + 1);
            float w2 = __shfl(w_own, base16 + j + 2);
            float w3 = __shfl(w_own, base16 + j + 3);
            half4 v0 = *(const half4*)&feat16[(size_t)s0 * FDIM + f];
            half4 v1 = *(const half4*)&feat16[(size_t)s1 * FDIM + f];
            half4 v2 = *(const half4*)&feat16[(size_t)s2 * FDIM + f];
            half4 v3 = *(const half4*)&feat16[(size_t)s3 * FDIM + f];
            acc.x += w0 * (float)v0[0] + w1 * (float)v1[0];
            acc.y += w0 * (float)v0[1] + w1 * (float)v1[1];
            acc.z += w0 * (float)v0[2] + w1 * (float)v1[2];
            acc.w += w0 * (float)v0[3] + w1 * (float)v1[3];
            acc.x += w2 * (float)v2[0] + w3 * (float)v3[0];
            acc.y += w2 * (float)v2[1] + w3 * (float)v3[1];
            acc.z += w2 * (float)v2[2] + w3 * (float)v3[2];
            acc.w += w2 * (float)v2[3] + w3 * (float)v3[3];
        }
        for (; j < rem; j++) {
            int s0 = __shfl(s_own, base16 + j);
            float w0 = __shfl(w_own, base16 + j);
            half4 v0 = *(const half4*)&feat16[(size_t)s0 * FDIM + f];
            acc.x += w0 * (float)v0[0];
            acc.y += w0 * (float)v0[1];
            acc.z += w0 * (float)v0[2];
            acc.w += w0 * (float)v0[3];
        }
    }

    // ---- reduce softmax denominator across the 16-lane head group
    ss += __shfl_xor(ss, 1, 16);
    ss += __shfl_xor(ss, 2, 16);
    ss += __shfl_xor(ss, 4, 16);
    ss += __shfl_xor(ss, 8, 16);

    float S = fmaxf(ss, 1e-9f);
    float inv = 1.f / S;
    float4 bv = *(const float4*)&bias[f];
    float r0 = acc.x * inv + bv.x;
    float r1 = acc.y * inv + bv.y;
    float r2 = acc.z * inv + bv.z;
    float r3 = acc.w * inv + bv.w;
    r0 = (r0 > 0.f) ? r0 : expm1f(r0);
    r1 = (r1 > 0.f) ? r1 : expm1f(r1);
    r2 = (r2 > 0.f) ? r2 : expm1f(r2);
    r3 = (r3 > 0.f) ? r3 : expm1f(r3);

    if (mode) {
        const int d = (lane & 15) * 4;
        float4 rv = make_float4(r0, r1, r2, r3);
        *(float4*)&out[(size_t)head * N_NODES * HID + (size_t)n * HID + d] = rv;
    } else {
        half4 hv = {(_Float16)r0, (_Float16)r1, (_Float16)r2, (_Float16)r3};
        *(half4*)&h1[(size_t)n * FDIM + f] = hv;
    }
}

// ---------------------------------------------------------------- launch

extern "C" void kernel_launch(void* const* d_in, const int* in_sizes, int n_in,
                              void* d_out, int out_size, void* d_ws, size_t ws_size,
                              hipStream_t stream) {
    const float* x   = (const float*)d_in[0];
    const int*   src = (const int*)d_in[1];
    const int*   dst = (const int*)d_in[2];
    const float* W0  = (const float*)d_in[3];
    const float* al0 = (const float*)d_in[4];
    const float* ar0 = (const float*)d_in[5];
    const float* b0  = (const float*)d_in[6];
    const float* W1  = (const float*)d_in[7];
    const float* al1 = (const float*)d_in[8];
    const float* ar1 = (const float*)d_in[9];
    const float* b1  = (const float*)d_in[10];
    float* out = (float*)d_out;

    // h1 (layer-1 hidden, fp16) lives in the first 25.6 MB of d_out.
    // Timeline: gemm-1 reads x fp32 directly -> agg(mode0) writes h1 ->
    // gemm-2 reads h1 -> agg(mode1) overwrites all of d_out with the final
    // output. All sequential on stream.
    _Float16* h1 = (_Float16*)d_out;

    // workspace layout
    _Float16* feat16 = (_Float16*)d_ws;                          // N*256 fp16
    _Float16* wt0 = feat16 + (size_t)N_NODES * FDIM;             // 256*256
    _Float16* wt1 = wt0 + FDIM * FDIM;                           // 256*256
    float* el    = (float*)(wt1 + FDIM * FDIM);                  // N*4
    float* er    = el + N_NODES * HEADS;                         // N*4
    int* counts  = (int*)(er + N_NODES * HEADS);                 // N
    int* cursor  = counts + N_NODES;                             // N
    int* offs    = cursor + N_NODES;                             // N+1 (pad 50016)
    int* bsum    = offs + 50016;                                 // 64
    int* csr_src = bsum + 64;                                    // E

    // ---- prep + CSR build
    hipMemsetAsync(counts, 0, 2 * N_NODES * sizeof(int), stream);  // counts + cursor
    wcast_kernel<<<dim3(16, 2), 256, 0, stream>>>(W0, W1, wt0, wt1);
    hist_kernel<<<(N_EDGES + 255) / 256, 256, 0, stream>>>(dst, counts, N_EDGES);
    scan_local<<<SCAN_NB, 256, 0, stream>>>(counts, offs, bsum, N_NODES);
    scan_bsum<<<1, 64, 0, stream>>>(bsum, offs, SCAN_NB, N_NODES);
    scan_add<<<SCAN_NB, 256, 0, stream>>>(offs, bsum, N_NODES);
    scatter_kernel<<<(N_EDGES + 255) / 256, 256, 0, stream>>>(src, dst, offs, cursor, csr_src, N_EDGES);

    const int ggrid = (N_NODES + 127) / 128;   // 391

    // ---- layer 1 (A from fp32 x; h1 fp16 written into d_out)
    mfma_gemm<1><<<ggrid, 512, 0, stream>>>(nullptr, x, wt0, al0, ar0, feat16, el, er);
    agg_fused<<<N_NODES / 4, 256, 0, stream>>>(feat16, el, er, b0, offs, csr_src,
                                               out, h1, 0);

    // ---- layer 2 (reads h1 fp16; final head-major fp32 write to d_out)
    mfma_gemm<0><<<ggrid, 512, 0, stream>>>(h1, nullptr, wt1, al1, ar1, feat16, el, er);
    agg_fused<<<N_NODES / 4, 256, 0, stream>>>(feat16, el, er, b1, offs, csr_src,
                                               out, h1, 1);
}